// Round 1
// baseline (588.057 us; speedup 1.0000x reference)
//
#include <hip/hip_runtime.h>

#define N_NODES 500000
#define N_CELLS 1000000
#define N_PTS   8000000

__global__ __launch_bounds__(256) void interp2d_quad_kernel(
    const float* __restrict__ nodal,  // (2, N_NODES)
    const float* __restrict__ sf,     // (N_PTS, 6)
    const int*   __restrict__ conn,   // (N_CELLS, 6), 1-based
    const int*   __restrict__ cid,    // (N_PTS,)
    float* __restrict__ out)          // (2, N_PTS)
{
    const int t  = blockIdx.x * blockDim.x + threadIdx.x;
    const int p0 = t * 2;
    if (p0 >= N_PTS) return;

    // two cell ids, coalesced 8B load
    const int2 c = *reinterpret_cast<const int2*>(cid + p0);

    // 12 shape-function floats for points p0, p0+1: 3 x float4 (16B aligned)
    const float4* sfp = reinterpret_cast<const float4*>(sf + (size_t)p0 * 6);
    const float4 s0 = sfp[0];
    const float4 s1 = sfp[1];
    const float4 s2 = sfp[2];

    const float w0[6] = { s0.x, s0.y, s0.z, s0.w, s1.x, s1.y };
    const float w1[6] = { s1.z, s1.w, s2.x, s2.y, s2.z, s2.w };

    float outd0[2], outd1[2];

    // point 0
    {
        const int* cr = conn + (size_t)c.x * 6;
        float a0 = 0.f, a1 = 0.f;
        #pragma unroll
        for (int k = 0; k < 6; ++k) {
            const int node = cr[k] - 1;
            const float nv0 = nodal[node];
            const float nv1 = nodal[N_NODES + node];
            a0 = fmaf(w0[k], nv0, a0);
            a1 = fmaf(w0[k], nv1, a1);
        }
        outd0[0] = a0; outd1[0] = a1;
    }
    // point 1
    {
        const int* cr = conn + (size_t)c.y * 6;
        float a0 = 0.f, a1 = 0.f;
        #pragma unroll
        for (int k = 0; k < 6; ++k) {
            const int node = cr[k] - 1;
            const float nv0 = nodal[node];
            const float nv1 = nodal[N_NODES + node];
            a0 = fmaf(w1[k], nv0, a0);
            a1 = fmaf(w1[k], nv1, a1);
        }
        outd0[1] = a0; outd1[1] = a1;
    }

    *reinterpret_cast<float2*>(out + p0)         = make_float2(outd0[0], outd0[1]);
    *reinterpret_cast<float2*>(out + N_PTS + p0) = make_float2(outd1[0], outd1[1]);
}

extern "C" void kernel_launch(void* const* d_in, const int* in_sizes, int n_in,
                              void* d_out, int out_size, void* d_ws, size_t ws_size,
                              hipStream_t stream) {
    const float* nodal = (const float*)d_in[0];  // (2, N_NODES)
    const float* sf    = (const float*)d_in[1];  // (N_PTS, 6)
    const int*   conn  = (const int*)d_in[2];    // (N_CELLS, 6)
    const int*   cid   = (const int*)d_in[3];    // (N_PTS,)
    float* out = (float*)d_out;                  // (2, N_PTS)

    const int threads = 256;
    const int total_thr = N_PTS / 2;             // 2 points per thread
    const int blocks = (total_thr + threads - 1) / threads;  // 15625
    interp2d_quad_kernel<<<blocks, threads, 0, stream>>>(nodal, sf, conn, cid, out);
}

// Round 2
// 254.128 us; speedup vs baseline: 2.3140x; 2.3140x over previous
//
#include <hip/hip_runtime.h>

#define N_NODES 500000
#define N_CELLS 1000000
#define N_PTS   8000000

// ---------------- Pass 1: gather per-cell nodal values ----------------
// cellvals[c] is a 64B row: [v0(n0), v1(n0), v0(n1), v1(n1), ..., v0(n5), v1(n5), pad*4]
__global__ __launch_bounds__(256) void gather_cellvals_kernel(
    const float* __restrict__ nodal,  // (2, N_NODES)
    const int*   __restrict__ conn,   // (N_CELLS, 6), 1-based
    float* __restrict__ cellvals)     // (N_CELLS, 16)
{
    const int c = blockIdx.x * blockDim.x + threadIdx.x;
    if (c >= N_CELLS) return;

    const int* cr = conn + (size_t)c * 6;
    float row[12];
    #pragma unroll
    for (int k = 0; k < 6; ++k) {
        const int node = cr[k] - 1;
        row[2 * k]     = nodal[node];
        row[2 * k + 1] = nodal[N_NODES + node];
    }
    float4* dst = reinterpret_cast<float4*>(cellvals + (size_t)c * 16);
    dst[0] = make_float4(row[0], row[1], row[2],  row[3]);
    dst[1] = make_float4(row[4], row[5], row[6],  row[7]);
    dst[2] = make_float4(row[8], row[9], row[10], row[11]);
    dst[3] = make_float4(0.f, 0.f, 0.f, 0.f);   // full 64B sector write (no RMW)
}

// ---------------- Pass 2: per-point interpolation ----------------
__global__ __launch_bounds__(256) void interp2d_cellvals_kernel(
    const float* __restrict__ cellvals, // (N_CELLS, 16)
    const float* __restrict__ sf,       // (N_PTS, 6)
    const int*   __restrict__ cid,      // (N_PTS,)
    float* __restrict__ out)            // (2, N_PTS)
{
    const int t  = blockIdx.x * blockDim.x + threadIdx.x;
    const int p0 = t * 2;
    if (p0 >= N_PTS) return;

    const int2 c = *reinterpret_cast<const int2*>(cid + p0);

    // 12 shape-function floats for points p0, p0+1 (16B aligned: 48B stride)
    const float4* sfp = reinterpret_cast<const float4*>(sf + (size_t)p0 * 6);
    const float4 s0 = sfp[0];
    const float4 s1 = sfp[1];
    const float4 s2 = sfp[2];

    // issue both cell rows up front (each = one 64B sector)
    const float4* r0 = reinterpret_cast<const float4*>(cellvals + (size_t)c.x * 16);
    const float4* r1 = reinterpret_cast<const float4*>(cellvals + (size_t)c.y * 16);
    const float4 q00 = r0[0], q01 = r0[1], q02 = r0[2];
    const float4 q10 = r1[0], q11 = r1[1], q12 = r1[2];

    // point 0 weights: s0.x..s1.y ; point 1 weights: s1.z..s2.w
    float a0, a1, b0, b1;
    a0 = s0.x * q00.x; a1 = s0.x * q00.y;
    a0 = fmaf(s0.y, q00.z, a0); a1 = fmaf(s0.y, q00.w, a1);
    a0 = fmaf(s0.z, q01.x, a0); a1 = fmaf(s0.z, q01.y, a1);
    a0 = fmaf(s0.w, q01.z, a0); a1 = fmaf(s0.w, q01.w, a1);
    a0 = fmaf(s1.x, q02.x, a0); a1 = fmaf(s1.x, q02.y, a1);
    a0 = fmaf(s1.y, q02.z, a0); a1 = fmaf(s1.y, q02.w, a1);

    b0 = s1.z * q10.x; b1 = s1.z * q10.y;
    b0 = fmaf(s1.w, q10.z, b0); b1 = fmaf(s1.w, q10.w, b1);
    b0 = fmaf(s2.x, q11.x, b0); b1 = fmaf(s2.x, q11.y, b1);
    b0 = fmaf(s2.y, q11.z, b0); b1 = fmaf(s2.y, q11.w, b1);
    b0 = fmaf(s2.z, q12.x, b0); b1 = fmaf(s2.z, q12.y, b1);
    b0 = fmaf(s2.w, q12.z, b0); b1 = fmaf(s2.w, q12.w, b1);

    *reinterpret_cast<float2*>(out + p0)         = make_float2(a0, b0);
    *reinterpret_cast<float2*>(out + N_PTS + p0) = make_float2(a1, b1);
}

// ---------------- Fallback (round-1 direct kernel) ----------------
__global__ __launch_bounds__(256) void interp2d_direct_kernel(
    const float* __restrict__ nodal,
    const float* __restrict__ sf,
    const int*   __restrict__ conn,
    const int*   __restrict__ cid,
    float* __restrict__ out)
{
    const int t  = blockIdx.x * blockDim.x + threadIdx.x;
    const int p0 = t * 2;
    if (p0 >= N_PTS) return;

    const int2 c = *reinterpret_cast<const int2*>(cid + p0);
    const float4* sfp = reinterpret_cast<const float4*>(sf + (size_t)p0 * 6);
    const float4 s0 = sfp[0];
    const float4 s1 = sfp[1];
    const float4 s2 = sfp[2];
    const float w0[6] = { s0.x, s0.y, s0.z, s0.w, s1.x, s1.y };
    const float w1[6] = { s1.z, s1.w, s2.x, s2.y, s2.z, s2.w };

    float o00 = 0.f, o01 = 0.f, o10 = 0.f, o11 = 0.f;
    {
        const int* cr = conn + (size_t)c.x * 6;
        #pragma unroll
        for (int k = 0; k < 6; ++k) {
            const int node = cr[k] - 1;
            o00 = fmaf(w0[k], nodal[node], o00);
            o01 = fmaf(w0[k], nodal[N_NODES + node], o01);
        }
    }
    {
        const int* cr = conn + (size_t)c.y * 6;
        #pragma unroll
        for (int k = 0; k < 6; ++k) {
            const int node = cr[k] - 1;
            o10 = fmaf(w1[k], nodal[node], o10);
            o11 = fmaf(w1[k], nodal[N_NODES + node], o11);
        }
    }
    *reinterpret_cast<float2*>(out + p0)         = make_float2(o00, o10);
    *reinterpret_cast<float2*>(out + N_PTS + p0) = make_float2(o01, o11);
}

extern "C" void kernel_launch(void* const* d_in, const int* in_sizes, int n_in,
                              void* d_out, int out_size, void* d_ws, size_t ws_size,
                              hipStream_t stream) {
    const float* nodal = (const float*)d_in[0];  // (2, N_NODES)
    const float* sf    = (const float*)d_in[1];  // (N_PTS, 6)
    const int*   conn  = (const int*)d_in[2];    // (N_CELLS, 6)
    const int*   cid   = (const int*)d_in[3];    // (N_PTS,)
    float* out = (float*)d_out;                  // (2, N_PTS)

    const size_t cellvals_bytes = (size_t)N_CELLS * 16 * sizeof(float); // 64 MB

    if (ws_size >= cellvals_bytes) {
        float* cellvals = (float*)d_ws;
        {
            const int threads = 256;
            const int blocks = (N_CELLS + threads - 1) / threads;
            gather_cellvals_kernel<<<blocks, threads, 0, stream>>>(nodal, conn, cellvals);
        }
        {
            const int threads = 256;
            const int blocks = (N_PTS / 2 + threads - 1) / threads;
            interp2d_cellvals_kernel<<<blocks, threads, 0, stream>>>(cellvals, sf, cid, out);
        }
    } else {
        const int threads = 256;
        const int blocks = (N_PTS / 2 + threads - 1) / threads;
        interp2d_direct_kernel<<<blocks, threads, 0, stream>>>(nodal, sf, conn, cid, out);
    }
}